// Round 1
// baseline (6799.024 us; speedup 1.0000x reference)
//
#include <hip/hip_runtime.h>
#include <hip/hip_bf16.h>

#define HH 512
#define WW 512
#define FEAT 256
#define C1 128
#define C2 64
#define NC 9

// ---------------- K1: features = hs @ proj_w + proj_b ----------------
__global__ __launch_bounds__(256) void proj_kernel(
    const float* __restrict__ hs, const float* __restrict__ pw,
    const float* __restrict__ pb, float* __restrict__ feat) {
  int row = blockIdx.x;          // b*S + s
  int f = threadIdx.x;           // 0..255
  const float* hrow = hs + (size_t)row * 768;
  float acc = pb[f];
  #pragma unroll 4
  for (int h = 0; h < 768; ++h) acc = fmaf(hrow[h], pw[h * 256 + f], acc);
  feat[row * 256 + f] = acc;
}

// ---------------- K2: winner map (last valid covering token) ----------------
__global__ __launch_bounds__(256) void winner_kernel(
    const int* __restrict__ bbox, const int* __restrict__ amask,
    int* __restrict__ winner) {
  __shared__ int sx1[512], sx2[512], sy1[512], sy2[512];
  int b = blockIdx.y;
  for (int s = threadIdx.x; s < 512; s += 256) {
    const int* bb = bbox + ((size_t)b * 512 + s) * 4;
    int x1 = (bb[0] * 512) / 1000; if (x1 < 0) x1 = 0;
    int y1 = (bb[1] * 512) / 1000; if (y1 < 0) y1 = 0;
    int x2 = (bb[2] * 512) / 1000; if (x2 > 511) x2 = 511;
    int y2 = (bb[3] * 512) / 1000; if (y2 > 511) y2 = 511;
    bool valid = (amask[b * 512 + s] == 1) && (s >= 1) && (x2 > x1) && (y2 > y1);
    if (!valid) { x1 = 512; x2 = -1; }   // cover test always false
    sx1[s] = x1; sx2[s] = x2; sy1[s] = y1; sy2[s] = y2;
  }
  __syncthreads();
  int p = blockIdx.x * 256 + threadIdx.x;   // 0..262143
  int h = p >> 9, w = p & 511;
  int win = 0;
  for (int s = 1; s < 512; ++s) {
    bool cov = (w >= sx1[s]) & (w < sx2[s]) & (h >= sy1[s]) & (h < sy2[s]);
    win = cov ? s : win;
  }
  winner[(b << 18) + p] = win;
}

// ---------------- K3: conv1 (gather-fused) + BN1 + ReLU -> buf1 ----------------
// buf1 layout: [oc 0..127][hh 0..SR+1][w 0..511], hh <-> global h = hstart + hh
__global__ __launch_bounds__(256, 2) void conv1_kernel(
    const float* __restrict__ feat, const int* __restrict__ winner,
    const float* __restrict__ w1, const float* __restrict__ cb,
    const float* __restrict__ g, const float* __restrict__ bt,
    const float* __restrict__ m, const float* __restrict__ v,
    float* __restrict__ buf1, int b, int hstart, int SR) {
  __shared__ int widx[340];
  __shared__ float patch[8 * 350];   // [ic][rr 0..9][cc 0..34], row stride 35
  __shared__ float wlds[2304];       // [ocl 0..31][icl 0..7][tap 0..8]
  int tid = threadIdx.x;
  int w0 = blockIdx.x * 32;
  int hh0 = blockIdx.y * 8;
  int oc0 = blockIdx.z * 32;
  int ocg = tid >> 6, pxg = tid & 63;
  int lh = pxg >> 3, lw0 = (pxg & 7) * 4;

  // stage winner indices for the 10x34 patch footprint (once)
  for (int i = tid; i < 340; i += 256) {
    int rr = i / 34, cc = i % 34;
    int hp = hstart + hh0 - 1 + rr;
    int wp = w0 - 1 + cc;
    int idx = 0;
    if (hp >= 0 && hp < HH && wp >= 0 && wp < WW)
      idx = winner[(b << 18) + (hp << 9) + wp];
    widx[i] = idx;
  }

  float scl[8], shf[8];
  #pragma unroll
  for (int j = 0; j < 8; ++j) {
    int oc = oc0 + ocg * 8 + j;
    float s = g[oc] * rsqrtf(v[oc] + 1e-5f);
    scl[j] = s;
    shf[j] = (cb[oc] - m[oc]) * s + bt[oc];
  }

  float acc[8][4];
  #pragma unroll
  for (int j = 0; j < 8; ++j)
    #pragma unroll
    for (int p = 0; p < 4; ++p) acc[j][p] = 0.f;

  for (int icb = 0; icb < 32; ++icb) {
    int ic0 = icb * 8;
    __syncthreads();   // patch free to overwrite (also covers widx on iter 0)
    for (int i = tid; i < 340; i += 256) {
      int rr = i / 34, cc = i % 34;
      int idx = widx[i];
      float4 va = make_float4(0.f, 0.f, 0.f, 0.f);
      float4 vb = make_float4(0.f, 0.f, 0.f, 0.f);
      if (idx > 0) {
        const float* fp = feat + ((((size_t)b << 9) + idx) << 8) + ic0;
        va = *(const float4*)fp;
        vb = *(const float4*)(fp + 4);
      }
      int base = rr * 35 + cc;
      patch[base]        = va.x; patch[base + 350]  = va.y;
      patch[base + 700]  = va.z; patch[base + 1050] = va.w;
      patch[base + 1400] = vb.x; patch[base + 1750] = vb.y;
      patch[base + 2100] = vb.z; patch[base + 2450] = vb.w;
    }
    for (int i = tid; i < 2304; i += 256) {
      int oc = i / 72, rem = i % 72;   // rem = icl*9 + tap
      wlds[i] = w1[(oc0 + oc) * 2304 + ic0 * 9 + rem];
    }
    __syncthreads();
    for (int ic = 0; ic < 8; ++ic) {
      const float* pbase = &patch[ic * 350 + lh * 35 + lw0];
      #pragma unroll
      for (int ky = 0; ky < 3; ++ky) {
        float xr[6];
        const float* pr = pbase + ky * 35;
        #pragma unroll
        for (int jj = 0; jj < 6; ++jj) xr[jj] = pr[jj];
        #pragma unroll
        for (int kx = 0; kx < 3; ++kx) {
          float wv[8];
          #pragma unroll
          for (int j = 0; j < 8; ++j)
            wv[j] = wlds[((ocg * 8 + j) * 8 + ic) * 9 + ky * 3 + kx];
          #pragma unroll
          for (int j = 0; j < 8; ++j) {
            acc[j][0] = fmaf(xr[kx + 0], wv[j], acc[j][0]);
            acc[j][1] = fmaf(xr[kx + 1], wv[j], acc[j][1]);
            acc[j][2] = fmaf(xr[kx + 2], wv[j], acc[j][2]);
            acc[j][3] = fmaf(xr[kx + 3], wv[j], acc[j][3]);
          }
        }
      }
    }
  }

  int hh = hh0 + lh;
  if (hh < SR + 2) {
    int h = hstart + hh;
    bool zero = (h < 0 || h >= HH);
    #pragma unroll
    for (int j = 0; j < 8; ++j) {
      int oc = oc0 + ocg * 8 + j;
      float4 o;
      o.x = zero ? 0.f : fmaxf(fmaf(acc[j][0], scl[j], shf[j]), 0.f);
      o.y = zero ? 0.f : fmaxf(fmaf(acc[j][1], scl[j], shf[j]), 0.f);
      o.z = zero ? 0.f : fmaxf(fmaf(acc[j][2], scl[j], shf[j]), 0.f);
      o.w = zero ? 0.f : fmaxf(fmaf(acc[j][3], scl[j], shf[j]), 0.f);
      *(float4*)&buf1[((size_t)oc * (SR + 2) + hh) * 512 + w0 + lw0] = o;
    }
  }
}

// ---------------- K4: conv2 + BN2 + ReLU -> buf2 ----------------
// buf2 layout: [oc 0..63][oh 0..SR-1][w], oh <-> global h = hs0 + oh
__global__ __launch_bounds__(256, 2) void conv2_kernel(
    const float* __restrict__ buf1, const float* __restrict__ w2,
    const float* __restrict__ cb, const float* __restrict__ g,
    const float* __restrict__ bt, const float* __restrict__ m,
    const float* __restrict__ v, float* __restrict__ buf2, int SR) {
  __shared__ float patch[8 * 350];
  __shared__ float wlds[2304];
  int tid = threadIdx.x;
  int w0 = blockIdx.x * 32;
  int oh0 = blockIdx.y * 8;
  int oc0 = blockIdx.z * 32;
  int ocg = tid >> 6, pxg = tid & 63;
  int lh = pxg >> 3, lw0 = (pxg & 7) * 4;

  float scl[8], shf[8];
  #pragma unroll
  for (int j = 0; j < 8; ++j) {
    int oc = oc0 + ocg * 8 + j;
    float s = g[oc] * rsqrtf(v[oc] + 1e-5f);
    scl[j] = s;
    shf[j] = (cb[oc] - m[oc]) * s + bt[oc];
  }

  float acc[8][4];
  #pragma unroll
  for (int j = 0; j < 8; ++j)
    #pragma unroll
    for (int p = 0; p < 4; ++p) acc[j][p] = 0.f;

  for (int icb = 0; icb < 16; ++icb) {
    int ic0 = icb * 8;
    __syncthreads();
    for (int i = tid; i < 340; i += 256) {
      int rr = i / 34, cc = i % 34;
      int wp = w0 - 1 + cc;
      int hr = oh0 + rr;                 // buf1 row, in [0, SR+2)
      bool okw = (wp >= 0) && (wp < WW);
      int base = rr * 35 + cc;
      #pragma unroll
      for (int ic = 0; ic < 8; ++ic) {
        float val = okw ? buf1[((size_t)(ic0 + ic) * (SR + 2) + hr) * 512 + wp] : 0.f;
        patch[ic * 350 + base] = val;
      }
    }
    for (int i = tid; i < 2304; i += 256) {
      int oc = i / 72, rem = i % 72;
      wlds[i] = w2[(oc0 + oc) * 1152 + ic0 * 9 + rem];
    }
    __syncthreads();
    for (int ic = 0; ic < 8; ++ic) {
      const float* pbase = &patch[ic * 350 + lh * 35 + lw0];
      #pragma unroll
      for (int ky = 0; ky < 3; ++ky) {
        float xr[6];
        const float* pr = pbase + ky * 35;
        #pragma unroll
        for (int jj = 0; jj < 6; ++jj) xr[jj] = pr[jj];
        #pragma unroll
        for (int kx = 0; kx < 3; ++kx) {
          float wv[8];
          #pragma unroll
          for (int j = 0; j < 8; ++j)
            wv[j] = wlds[((ocg * 8 + j) * 8 + ic) * 9 + ky * 3 + kx];
          #pragma unroll
          for (int j = 0; j < 8; ++j) {
            acc[j][0] = fmaf(xr[kx + 0], wv[j], acc[j][0]);
            acc[j][1] = fmaf(xr[kx + 1], wv[j], acc[j][1]);
            acc[j][2] = fmaf(xr[kx + 2], wv[j], acc[j][2]);
            acc[j][3] = fmaf(xr[kx + 3], wv[j], acc[j][3]);
          }
        }
      }
    }
  }

  int oh = oh0 + lh;
  #pragma unroll
  for (int j = 0; j < 8; ++j) {
    int oc = oc0 + ocg * 8 + j;
    float4 o;
    o.x = fmaxf(fmaf(acc[j][0], scl[j], shf[j]), 0.f);
    o.y = fmaxf(fmaf(acc[j][1], scl[j], shf[j]), 0.f);
    o.z = fmaxf(fmaf(acc[j][2], scl[j], shf[j]), 0.f);
    o.w = fmaxf(fmaf(acc[j][3], scl[j], shf[j]), 0.f);
    *(float4*)&buf2[((size_t)oc * SR + oh) * 512 + w0 + lw0] = o;
  }
}

// ---------------- K5: conv3 (1x1, 64->9) -> d_out ----------------
__global__ __launch_bounds__(256) void conv3_kernel(
    const float* __restrict__ buf2, const float* __restrict__ w3,
    const float* __restrict__ b3, float* __restrict__ out,
    int b, int hs0, int SR) {
  __shared__ float w3s[NC * 64];
  __shared__ float b3s[NC];
  for (int i = threadIdx.x; i < NC * 64; i += 256) w3s[i] = w3[i];
  if (threadIdx.x < NC) b3s[threadIdx.x] = b3[threadIdx.x];
  __syncthreads();
  int p = blockIdx.x * 256 + threadIdx.x;   // < SR*512
  float acc[NC];
  #pragma unroll
  for (int c = 0; c < NC; ++c) acc[c] = b3s[c];
  for (int ic = 0; ic < 64; ++ic) {
    float val = buf2[(size_t)ic * SR * 512 + p];
    #pragma unroll
    for (int c = 0; c < NC; ++c) acc[c] = fmaf(w3s[c * 64 + ic], val, acc[c]);
  }
  size_t base = (size_t)b * NC * 262144 + (size_t)hs0 * 512 + p;
  #pragma unroll
  for (int c = 0; c < NC; ++c) out[base + (size_t)c * 262144] = acc[c];
}

extern "C" void kernel_launch(void* const* d_in, const int* in_sizes, int n_in,
                              void* d_out, int out_size, void* d_ws, size_t ws_size,
                              hipStream_t stream) {
  const float* hs  = (const float*)d_in[0];
  const int* bbox  = (const int*)d_in[1];
  const int* amask = (const int*)d_in[2];
  const float* pw  = (const float*)d_in[3];
  const float* pb  = (const float*)d_in[4];
  const float* w1  = (const float*)d_in[5];
  const float* c1b = (const float*)d_in[6];
  const float* g1  = (const float*)d_in[7];
  const float* b1  = (const float*)d_in[8];
  const float* m1  = (const float*)d_in[9];
  const float* v1  = (const float*)d_in[10];
  const float* w2  = (const float*)d_in[11];
  const float* c2b = (const float*)d_in[12];
  const float* g2  = (const float*)d_in[13];
  const float* b2  = (const float*)d_in[14];
  const float* m2  = (const float*)d_in[15];
  const float* v2  = (const float*)d_in[16];
  const float* w3  = (const float*)d_in[17];
  const float* b3  = (const float*)d_in[18];
  float* out = (float*)d_out;

  char* wsb = (char*)d_ws;
  float* feat = (float*)wsb;                    // 262144 floats = 1 MB
  int* winner = (int*)(wsb + (1 << 20));        // 524288 ints  = 2 MB
  char* bufbase = wsb + (3 << 20);

  // pick largest stripe that fits the workspace
  int SR = 128;
  while (SR > 8) {
    size_t need = (size_t)(3 << 20) +
                  ((size_t)(SR + 2) * 512 * C1 + (size_t)SR * 512 * C2) * 4;
    if (need <= ws_size) break;
    SR >>= 1;
  }
  float* buf1 = (float*)bufbase;
  float* buf2 = buf1 + (size_t)(SR + 2) * 512 * C1;

  proj_kernel<<<1024, 256, 0, stream>>>(hs, pw, pb, feat);
  winner_kernel<<<dim3(1024, 2), 256, 0, stream>>>(bbox, amask, winner);

  int nstripes = 512 / SR;
  for (int b = 0; b < 2; ++b) {
    for (int s = 0; s < nstripes; ++s) {
      int hs0 = s * SR;
      conv1_kernel<<<dim3(16, (SR + 2 + 7) / 8, 4), 256, 0, stream>>>(
          feat, winner, w1, c1b, g1, b1, m1, v1, buf1, b, hs0 - 1, SR);
      conv2_kernel<<<dim3(16, SR / 8, 2), 256, 0, stream>>>(
          buf1, w2, c2b, g2, b2, m2, v2, buf2, SR);
      conv3_kernel<<<dim3(SR * 2), 256, 0, stream>>>(
          buf2, w3, b3, out, b, hs0, SR);
    }
  }
}

// Round 2
// 1616.490 us; speedup vs baseline: 4.2060x; 4.2060x over previous
//
#include <hip/hip_runtime.h>
#include <hip/hip_bf16.h>

#define HH 512
#define WW 512
#define FEAT 256
#define C1 128
#define C2 64
#define NC 9

// ---------------- K1: features = hs @ proj_w + proj_b ----------------
__global__ __launch_bounds__(256) void proj_kernel(
    const float* __restrict__ hs, const float* __restrict__ pw,
    const float* __restrict__ pb, float* __restrict__ feat) {
  int row = blockIdx.x;          // b*S + s
  int f = threadIdx.x;           // 0..255
  const float* hrow = hs + (size_t)row * 768;
  float acc = pb[f];
  #pragma unroll 4
  for (int h = 0; h < 768; ++h) acc = fmaf(hrow[h], pw[h * 256 + f], acc);
  feat[row * 256 + f] = acc;
}

// ---------------- K2: winner map (last valid covering token) ----------------
__global__ __launch_bounds__(256) void winner_kernel(
    const int* __restrict__ bbox, const int* __restrict__ amask,
    int* __restrict__ winner) {
  __shared__ int sx1[512], sx2[512], sy1[512], sy2[512];
  int b = blockIdx.y;
  for (int s = threadIdx.x; s < 512; s += 256) {
    const int* bb = bbox + ((size_t)b * 512 + s) * 4;
    int x1 = (bb[0] * 512) / 1000; if (x1 < 0) x1 = 0;
    int y1 = (bb[1] * 512) / 1000; if (y1 < 0) y1 = 0;
    int x2 = (bb[2] * 512) / 1000; if (x2 > 511) x2 = 511;
    int y2 = (bb[3] * 512) / 1000; if (y2 > 511) y2 = 511;
    bool valid = (amask[b * 512 + s] == 1) && (s >= 1) && (x2 > x1) && (y2 > y1);
    if (!valid) { x1 = 512; x2 = -1; }   // cover test always false
    sx1[s] = x1; sx2[s] = x2; sy1[s] = y1; sy2[s] = y2;
  }
  __syncthreads();
  int p = blockIdx.x * 256 + threadIdx.x;   // 0..262143
  int h = p >> 9, w = p & 511;
  int win = 0;
  for (int s = 1; s < 512; ++s) {
    bool cov = (w >= sx1[s]) & (w < sx2[s]) & (h >= sy1[s]) & (h < sy2[s]);
    win = cov ? s : win;
  }
  winner[(b << 18) + p] = win;
}

// ---------------- K2.5: per-tap transformed features ----------------
// G[b][s][tap][oc]  = sum_ic feat[b,s,ic] * w1[oc,ic,tap]      (s==0 -> 0)
// Gall[b][s][oc]    = sum_tap G[b][s][tap][oc]
__global__ __launch_bounds__(128) void gtab_kernel(
    const float* __restrict__ feat, const float* __restrict__ w1,
    float* __restrict__ G, float* __restrict__ Gall) {
  int b = blockIdx.x >> 7;              // grid.x = 256
  int s0 = (blockIdx.x & 127) * 4;
  __shared__ float sfeat[4 * 256];
  int oc = threadIdx.x;                 // 0..127
  for (int i = oc; i < 1024; i += 128)
    sfeat[i] = feat[(((size_t)b << 9) + s0) * 256 + i];
  __syncthreads();

  float acc[4][9];
  #pragma unroll
  for (int to = 0; to < 4; ++to)
    #pragma unroll
    for (int t = 0; t < 9; ++t) acc[to][t] = 0.f;

  const float* wrow = w1 + (size_t)oc * 2304;
  for (int ic = 0; ic < 256; ++ic) {
    float w[9];
    #pragma unroll
    for (int t = 0; t < 9; ++t) w[t] = wrow[ic * 9 + t];
    #pragma unroll
    for (int to = 0; to < 4; ++to) {
      float f = sfeat[to * 256 + ic];
      #pragma unroll
      for (int t = 0; t < 9; ++t) acc[to][t] = fmaf(f, w[t], acc[to][t]);
    }
  }

  #pragma unroll
  for (int to = 0; to < 4; ++to) {
    int s = s0 + to;
    float msk = (s > 0) ? 1.f : 0.f;    // token 0 / empty -> zero row
    float sum = 0.f;
    size_t base = (((size_t)b << 9) + s) * 1152;
    #pragma unroll
    for (int t = 0; t < 9; ++t) {
      float vv = acc[to][t] * msk;
      G[base + t * 128 + oc] = vv;
      sum += vv;
    }
    Gall[(((size_t)b << 9) + s) * 128 + oc] = sum;
  }
}

// ---------------- K3: conv1 via gather-add of G + BN1 + ReLU -> buf1 ----------------
// buf1 layout: [oc 0..127][hh 0..SR+1][w 0..511], hh <-> global h = hstart + hh
__global__ __launch_bounds__(256) void conv1_gather_kernel(
    const int* __restrict__ winner, const float* __restrict__ G,
    const float* __restrict__ Gall,
    const float* __restrict__ cb, const float* __restrict__ g,
    const float* __restrict__ bt, const float* __restrict__ m,
    const float* __restrict__ v,
    float* __restrict__ buf1, int b, int hstart, int SR) {
  __shared__ float sscl[64], sshf[64];
  int tid = threadIdx.x;
  int oc0 = blockIdx.z * 64;
  if (tid < 64) {
    int oc = oc0 + tid;
    float s = g[oc] * rsqrtf(v[oc] + 1e-5f);
    sscl[tid] = s;
    sshf[tid] = (cb[oc] - m[oc]) * s + bt[oc];
  }
  __syncthreads();

  int wl = tid & 63, hl = tid >> 6;
  int w = blockIdx.x * 64 + wl;
  int hh = blockIdx.y * 4 + hl;
  if (hh >= SR + 2) return;
  int h = hstart + hh;
  float* orow = buf1 + ((size_t)oc0 * (SR + 2) + hh) * 512 + w;
  size_t ocplane = (size_t)(SR + 2) * 512;

  if (h < 0 || h >= HH) {               // halo outside image: zeros
    for (int ocl = 0; ocl < 64; ++ocl) orow[ocl * ocplane] = 0.f;
    return;
  }

  // 9 neighborhood winners
  int win[9];
  #pragma unroll
  for (int ky = 0; ky < 3; ++ky)
    #pragma unroll
    for (int kx = 0; kx < 3; ++kx) {
      int hp = h - 1 + ky, wp = w - 1 + kx;
      int s = 0;
      if (hp >= 0 && hp < HH && wp >= 0 && wp < WW)
        s = winner[(b << 18) + (hp << 9) + wp];
      win[ky * 3 + kx] = s;
    }
  bool alleq = true;
  #pragma unroll
  for (int t = 1; t < 9; ++t) alleq = alleq && (win[t] == win[0]);

  const float* Gb = G + (((size_t)b << 9)) * 1152;
  const float* gallrow = Gall + (((size_t)b << 9) + win[0]) * 128 + oc0;
  int off[9];
  #pragma unroll
  for (int t = 0; t < 9; ++t) off[t] = win[t] * 1152 + t * 128 + oc0;

  #pragma unroll 4
  for (int o4 = 0; o4 < 16; ++o4) {
    float4 a;
    if (alleq) {
      a = *(const float4*)(gallrow + o4 * 4);
    } else {
      a = make_float4(0.f, 0.f, 0.f, 0.f);
      #pragma unroll
      for (int t = 0; t < 9; ++t) {
        float4 gv = *(const float4*)(Gb + off[t] + o4 * 4);
        a.x += gv.x; a.y += gv.y; a.z += gv.z; a.w += gv.w;
      }
    }
    int ocl = o4 * 4;
    orow[(ocl + 0) * ocplane] = fmaxf(fmaf(a.x, sscl[ocl + 0], sshf[ocl + 0]), 0.f);
    orow[(ocl + 1) * ocplane] = fmaxf(fmaf(a.y, sscl[ocl + 1], sshf[ocl + 1]), 0.f);
    orow[(ocl + 2) * ocplane] = fmaxf(fmaf(a.z, sscl[ocl + 2], sshf[ocl + 2]), 0.f);
    orow[(ocl + 3) * ocplane] = fmaxf(fmaf(a.w, sscl[ocl + 3], sshf[ocl + 3]), 0.f);
  }
}

// ---------------- K4: conv2 + BN2 + ReLU -> buf2 ----------------
// buf2 layout: [oc 0..63][oh 0..SR-1][w], oh <-> global h = hs0 + oh
__global__ __launch_bounds__(256) void conv2_kernel(
    const float* __restrict__ buf1, const float* __restrict__ w2,
    const float* __restrict__ cb, const float* __restrict__ g,
    const float* __restrict__ bt, const float* __restrict__ m,
    const float* __restrict__ v, float* __restrict__ buf2, int SR) {
  __shared__ float patch[8 * 360];   // [ic][rr 0..9][cc 0..35], row stride 36
  __shared__ float wlds[1152];       // [ic 0..7][tap 0..8][ocl 0..15]
  int tid = threadIdx.x;
  int w0 = blockIdx.x * 32;
  int oh0 = blockIdx.y * 8;
  int oc0 = blockIdx.z * 16;
  int ocg = tid >> 6, pxg = tid & 63;
  int lh = pxg >> 3, lw0 = (pxg & 7) * 4;

  float scl[4], shf[4];
  #pragma unroll
  for (int j = 0; j < 4; ++j) {
    int oc = oc0 + ocg * 4 + j;
    float s = g[oc] * rsqrtf(v[oc] + 1e-5f);
    scl[j] = s;
    shf[j] = (cb[oc] - m[oc]) * s + bt[oc];
  }

  float acc[4][4];
  #pragma unroll
  for (int j = 0; j < 4; ++j)
    #pragma unroll
    for (int p = 0; p < 4; ++p) acc[j][p] = 0.f;

  for (int icb = 0; icb < 16; ++icb) {
    int ic0 = icb * 8;
    __syncthreads();
    for (int i = tid; i < 340; i += 256) {
      int rr = i / 34, cc = i % 34;
      int wp = w0 - 1 + cc;
      int hr = oh0 + rr;                 // buf1 row, in [0, SR+2)
      bool okw = (wp >= 0) && (wp < WW);
      int base = rr * 36 + cc;
      #pragma unroll
      for (int ic = 0; ic < 8; ++ic) {
        float val = okw ? buf1[((size_t)(ic0 + ic) * (SR + 2) + hr) * 512 + wp] : 0.f;
        patch[ic * 360 + base] = val;
      }
    }
    for (int i = tid; i < 1152; i += 256) {
      int ic = i / 144, rem = i % 144;
      int tap = rem / 16, oc = rem & 15;
      wlds[i] = w2[(size_t)(oc0 + oc) * 1152 + (ic0 + ic) * 9 + tap];
    }
    __syncthreads();
    #pragma unroll 2
    for (int ic = 0; ic < 8; ++ic) {
      const float* pb_ = &patch[ic * 360 + lh * 36 + lw0];
      #pragma unroll
      for (int ky = 0; ky < 3; ++ky) {
        float4 xa = *(const float4*)(pb_ + ky * 36);
        float4 xb = *(const float4*)(pb_ + ky * 36 + 4);
        float xr[6] = {xa.x, xa.y, xa.z, xa.w, xb.x, xb.y};
        #pragma unroll
        for (int kx = 0; kx < 3; ++kx) {
          float4 wv = *(const float4*)&wlds[(ic * 9 + ky * 3 + kx) * 16 + ocg * 4];
          float wv4[4] = {wv.x, wv.y, wv.z, wv.w};
          #pragma unroll
          for (int j = 0; j < 4; ++j) {
            acc[j][0] = fmaf(xr[kx + 0], wv4[j], acc[j][0]);
            acc[j][1] = fmaf(xr[kx + 1], wv4[j], acc[j][1]);
            acc[j][2] = fmaf(xr[kx + 2], wv4[j], acc[j][2]);
            acc[j][3] = fmaf(xr[kx + 3], wv4[j], acc[j][3]);
          }
        }
      }
    }
  }

  int oh = oh0 + lh;
  #pragma unroll
  for (int j = 0; j < 4; ++j) {
    int oc = oc0 + ocg * 4 + j;
    float4 o;
    o.x = fmaxf(fmaf(acc[j][0], scl[j], shf[j]), 0.f);
    o.y = fmaxf(fmaf(acc[j][1], scl[j], shf[j]), 0.f);
    o.z = fmaxf(fmaf(acc[j][2], scl[j], shf[j]), 0.f);
    o.w = fmaxf(fmaf(acc[j][3], scl[j], shf[j]), 0.f);
    *(float4*)&buf2[((size_t)oc * SR + oh) * 512 + w0 + lw0] = o;
  }
}

// ---------------- K5: conv3 (1x1, 64->9) -> d_out ----------------
__global__ __launch_bounds__(256) void conv3_kernel(
    const float* __restrict__ buf2, const float* __restrict__ w3,
    const float* __restrict__ b3, float* __restrict__ out,
    int b, int hs0, int SR) {
  __shared__ float w3s[NC * 64];
  __shared__ float b3s[NC];
  for (int i = threadIdx.x; i < NC * 64; i += 256) w3s[i] = w3[i];
  if (threadIdx.x < NC) b3s[threadIdx.x] = b3[threadIdx.x];
  __syncthreads();
  int p = blockIdx.x * 256 + threadIdx.x;   // < SR*512
  float acc[NC];
  #pragma unroll
  for (int c = 0; c < NC; ++c) acc[c] = b3s[c];
  for (int ic = 0; ic < 64; ++ic) {
    float val = buf2[(size_t)ic * SR * 512 + p];
    #pragma unroll
    for (int c = 0; c < NC; ++c) acc[c] = fmaf(w3s[c * 64 + ic], val, acc[c]);
  }
  size_t base = (size_t)b * NC * 262144 + (size_t)hs0 * 512 + p;
  #pragma unroll
  for (int c = 0; c < NC; ++c) out[base + (size_t)c * 262144] = acc[c];
}

extern "C" void kernel_launch(void* const* d_in, const int* in_sizes, int n_in,
                              void* d_out, int out_size, void* d_ws, size_t ws_size,
                              hipStream_t stream) {
  const float* hs  = (const float*)d_in[0];
  const int* bbox  = (const int*)d_in[1];
  const int* amask = (const int*)d_in[2];
  const float* pw  = (const float*)d_in[3];
  const float* pb  = (const float*)d_in[4];
  const float* w1  = (const float*)d_in[5];
  const float* c1b = (const float*)d_in[6];
  const float* g1  = (const float*)d_in[7];
  const float* b1  = (const float*)d_in[8];
  const float* m1  = (const float*)d_in[9];
  const float* v1  = (const float*)d_in[10];
  const float* w2  = (const float*)d_in[11];
  const float* c2b = (const float*)d_in[12];
  const float* g2  = (const float*)d_in[13];
  const float* b2  = (const float*)d_in[14];
  const float* m2  = (const float*)d_in[15];
  const float* v2  = (const float*)d_in[16];
  const float* w3  = (const float*)d_in[17];
  const float* b3  = (const float*)d_in[18];
  float* out = (float*)d_out;

  char* wsb = (char*)d_ws;
  float* feat   = (float*)wsb;                       // 1 MB
  int*   winner = (int*)(wsb + (1 << 20));           // 2 MB
  float* G      = (float*)(wsb + (3 << 20));         // 2*512*9*128*4 = 4.5 MB
  float* Gall   = (float*)(wsb + (3 << 20) + 4718592); // 0.5 MB -> ends at 8 MB
  char* bufbase = wsb + (8 << 20);

  // pick largest stripe that fits the workspace
  int SR = 256;
  while (SR > 8) {
    size_t need = (size_t)(8 << 20) +
                  ((size_t)(SR + 2) * 512 * C1 + (size_t)SR * 512 * C2) * 4;
    if (need <= ws_size) break;
    SR >>= 1;
  }
  float* buf1 = (float*)bufbase;
  float* buf2 = buf1 + (size_t)(SR + 2) * 512 * C1;

  proj_kernel<<<1024, 256, 0, stream>>>(hs, pw, pb, feat);
  winner_kernel<<<dim3(1024, 2), 256, 0, stream>>>(bbox, amask, winner);
  gtab_kernel<<<256, 128, 0, stream>>>(feat, w1, G, Gall);

  int nstripes = 512 / SR;
  for (int b = 0; b < 2; ++b) {
    for (int s = 0; s < nstripes; ++s) {
      int hs0 = s * SR;
      conv1_gather_kernel<<<dim3(8, (SR + 2 + 3) / 4, 2), 256, 0, stream>>>(
          winner, G, Gall, c1b, g1, b1, m1, v1, buf1, b, hs0 - 1, SR);
      conv2_kernel<<<dim3(16, SR / 8, 4), 256, 0, stream>>>(
          buf1, w2, c2b, g2, b2, m2, v2, buf2, SR);
      conv3_kernel<<<dim3(SR * 2), 256, 0, stream>>>(
          buf2, w3, b3, out, b, hs0, SR);
    }
  }
}

// Round 3
// 400.714 us; speedup vs baseline: 16.9673x; 4.0340x over previous
//
#include <hip/hip_runtime.h>
#include <hip/hip_bf16.h>

typedef __bf16 bf16x8 __attribute__((ext_vector_type(8)));
typedef float f32x4 __attribute__((ext_vector_type(4)));

#define HH 512
#define WW 512
#define NC 9
#define LDSB 16896
#define SCRATCH_OFF 0
#define W3_OFF 33792
#define B3_OFF 36096

static __device__ __forceinline__ ushort f2bf(float x) {
  union { float f; unsigned u; } c; c.f = x;
  unsigned r = c.u + 0x7FFFu + ((c.u >> 16) & 1u);
  return (ushort)(r >> 16);
}

// ---------------- K1: features = hs @ proj_w + proj_b ----------------
__global__ __launch_bounds__(256) void proj_kernel(
    const float* __restrict__ hs, const float* __restrict__ pw,
    const float* __restrict__ pb, float* __restrict__ feat) {
  int row = blockIdx.x;
  int f = threadIdx.x;
  const float* hrow = hs + (size_t)row * 768;
  float acc = pb[f];
  #pragma unroll 4
  for (int h = 0; h < 768; ++h) acc = fmaf(hrow[h], pw[h * 256 + f], acc);
  feat[row * 256 + f] = acc;
}

// ---------------- K2: winner map ----------------
__global__ __launch_bounds__(256) void winner_kernel(
    const int* __restrict__ bbox, const int* __restrict__ amask,
    int* __restrict__ winner) {
  __shared__ int sx1[512], sx2[512], sy1[512], sy2[512];
  int b = blockIdx.y;
  for (int s = threadIdx.x; s < 512; s += 256) {
    const int* bb = bbox + ((size_t)b * 512 + s) * 4;
    int x1 = (bb[0] * 512) / 1000; if (x1 < 0) x1 = 0;
    int y1 = (bb[1] * 512) / 1000; if (y1 < 0) y1 = 0;
    int x2 = (bb[2] * 512) / 1000; if (x2 > 511) x2 = 511;
    int y2 = (bb[3] * 512) / 1000; if (y2 > 511) y2 = 511;
    bool valid = (amask[b * 512 + s] == 1) && (s >= 1) && (x2 > x1) && (y2 > y1);
    if (!valid) { x1 = 512; x2 = -1; }
    sx1[s] = x1; sx2[s] = x2; sy1[s] = y1; sy2[s] = y2;
  }
  __syncthreads();
  int p = blockIdx.x * 256 + threadIdx.x;
  int h = p >> 9, w = p & 511;
  int win = 0;
  for (int s = 1; s < 512; ++s) {
    bool cov = (w >= sx1[s]) & (w < sx2[s]) & (h >= sy1[s]) & (h < sy2[s]);
    win = cov ? s : win;
  }
  winner[(b << 18) + p] = win;
}

// ---------------- K2.5: G tables ----------------
__global__ __launch_bounds__(128) void gtab_kernel(
    const float* __restrict__ feat, const float* __restrict__ w1,
    float* __restrict__ G, float* __restrict__ Gall) {
  int b = blockIdx.x >> 7;
  int s0 = (blockIdx.x & 127) * 4;
  __shared__ float sfeat[4 * 256];
  int oc = threadIdx.x;
  for (int i = oc; i < 1024; i += 128)
    sfeat[i] = feat[(((size_t)b << 9) + s0) * 256 + i];
  __syncthreads();

  float acc[4][9];
  #pragma unroll
  for (int to = 0; to < 4; ++to)
    #pragma unroll
    for (int t = 0; t < 9; ++t) acc[to][t] = 0.f;

  const float* wrow = w1 + (size_t)oc * 2304;
  for (int ic = 0; ic < 256; ++ic) {
    float w[9];
    #pragma unroll
    for (int t = 0; t < 9; ++t) w[t] = wrow[ic * 9 + t];
    #pragma unroll
    for (int to = 0; to < 4; ++to) {
      float f = sfeat[to * 256 + ic];
      #pragma unroll
      for (int t = 0; t < 9; ++t) acc[to][t] = fmaf(f, w[t], acc[to][t]);
    }
  }

  #pragma unroll
  for (int to = 0; to < 4; ++to) {
    int s = s0 + to;
    float msk = (s > 0) ? 1.f : 0.f;
    float sum = 0.f;
    size_t base = (((size_t)b << 9) + s) * 1152;
    #pragma unroll
    for (int t = 0; t < 9; ++t) {
      float vv = acc[to][t] * msk;
      G[base + t * 128 + oc] = vv;
      sum += vv;
    }
    Gall[(((size_t)b << 9) + s) * 128 + oc] = sum;
  }
}

// ---------------- K2.6: aux = uniform-window map ----------------
__global__ __launch_bounds__(256) void aux_kernel(
    const int* __restrict__ winner, int* __restrict__ aux) {
  int idx = blockIdx.x * 256 + threadIdx.x;   // < 524288
  int b = idx >> 18, p = idx & 262143;
  int h = p >> 9, w = p & 511;
  const int* wb = winner + (b << 18);
  int s0 = 0; bool eq = true; bool first = true;
  #pragma unroll
  for (int ky = 0; ky < 3; ++ky)
    #pragma unroll
    for (int kx = 0; kx < 3; ++kx) {
      int hp = h - 1 + ky, wp = w - 1 + kx;
      int s = 0;
      if (hp >= 0 && hp < HH && wp >= 0 && wp < WW) s = wb[(hp << 9) + wp];
      if (first) { s0 = s; first = false; }
      else eq = eq && (s == s0);
    }
  aux[idx] = eq ? s0 : -1;
}

// ---------------- K2.7: w2T[oc][tap*128+ic] bf16 ----------------
__global__ __launch_bounds__(256) void w2t_kernel(
    const float* __restrict__ w2, ushort* __restrict__ w2t) {
  int oc = blockIdx.x;
  for (int k = threadIdx.x; k < 1152; k += 256) {
    int tap = k >> 7, ic = k & 127;
    w2t[(size_t)oc * 1152 + k] = f2bf(w2[(size_t)oc * 1152 + ic * 9 + tap]);
  }
}

// ---------------- K3: conv1 gather + BN1 + ReLU -> buf1 (bf16 NHWC) ----------------
// buf1: [(SR+2) rows][512 w][128 ic] bf16 ; row i <-> global h = hstart + i
__global__ __launch_bounds__(256) void conv1_gather_kernel(
    const int* __restrict__ winner, const int* __restrict__ aux,
    const float* __restrict__ G, const float* __restrict__ Gall,
    const float* __restrict__ cb, const float* __restrict__ g,
    const float* __restrict__ bt, const float* __restrict__ m,
    const float* __restrict__ v,
    ushort* __restrict__ buf1, int b, int hstart) {
  __shared__ float sscl[128], sshf[128];
  int tid = threadIdx.x;
  if (tid < 128) {
    float s = g[tid] * rsqrtf(v[tid] + 1e-5f);
    sscl[tid] = s;
    sshf[tid] = (cb[tid] - m[tid]) * s + bt[tid];
  }
  __syncthreads();
  int px = blockIdx.x * 32 + (tid >> 3);
  int gq = tid & 7;
  int r = px >> 9, w = px & 511;
  int h = hstart + r;
  ushort* dst = buf1 + (size_t)px * 128 + gq * 16;
  if (h < 0 || h >= HH) {
    uint4 z = make_uint4(0, 0, 0, 0);
    *(uint4*)dst = z; *(uint4*)(dst + 8) = z;
    return;
  }
  int a = aux[(b << 18) + (h << 9) + w];
  float4 a0, a1, a2, a3;
  if (a >= 0) {
    const float4* gp = (const float4*)(Gall + ((((size_t)b << 9) + a) << 7) + gq * 16);
    a0 = gp[0]; a1 = gp[1]; a2 = gp[2]; a3 = gp[3];
  } else {
    a0 = make_float4(0,0,0,0); a1 = a0; a2 = a0; a3 = a0;
    const int* wb = winner + (b << 18);
    #pragma unroll
    for (int ky = 0; ky < 3; ++ky)
      #pragma unroll
      for (int kx = 0; kx < 3; ++kx) {
        int hp = h - 1 + ky, wp = w - 1 + kx;
        int s = 0;
        if (hp >= 0 && hp < HH && wp >= 0 && wp < WW) s = wb[(hp << 9) + wp];
        int tap = ky * 3 + kx;
        const float4* gp = (const float4*)(G + ((size_t)((b << 9) + s)) * 1152 + tap * 128 + gq * 16);
        float4 g0 = gp[0], g1 = gp[1], g2 = gp[2], g3 = gp[3];
        a0.x += g0.x; a0.y += g0.y; a0.z += g0.z; a0.w += g0.w;
        a1.x += g1.x; a1.y += g1.y; a1.z += g1.z; a1.w += g1.w;
        a2.x += g2.x; a2.y += g2.y; a2.z += g2.z; a2.w += g2.w;
        a3.x += g3.x; a3.y += g3.y; a3.z += g3.z; a3.w += g3.w;
      }
  }
  const float* sc = &sscl[gq * 16];
  const float* sh = &sshf[gq * 16];
  union { ushort us[8]; uint4 v4; } p0, p1;
  float fv[16] = {a0.x,a0.y,a0.z,a0.w, a1.x,a1.y,a1.z,a1.w,
                  a2.x,a2.y,a2.z,a2.w, a3.x,a3.y,a3.z,a3.w};
  #pragma unroll
  for (int j = 0; j < 8; ++j)
    p0.us[j] = f2bf(fmaxf(fmaf(fv[j], sc[j], sh[j]), 0.f));
  #pragma unroll
  for (int j = 0; j < 8; ++j)
    p1.us[j] = f2bf(fmaxf(fmaf(fv[8 + j], sc[8 + j], sh[8 + j]), 0.f));
  *(uint4*)dst = p0.v4;
  *(uint4*)(dst + 8) = p1.v4;
}

// ---------------- K4: conv2 MFMA (implicit GEMM) + BN2 + ReLU + fused conv3 ----------------
// block: 256 thr = 4 waves; tile M=128 px (2 rows x 64 w) x N=64 oc; wave 64x32.
__global__ __launch_bounds__(256) void conv2_mfma_kernel(
    const ushort* __restrict__ buf1, const ushort* __restrict__ w2t,
    const float* __restrict__ cb, const float* __restrict__ g,
    const float* __restrict__ bt, const float* __restrict__ m_,
    const float* __restrict__ v_,
    const float* __restrict__ w3, const float* __restrict__ b3,
    float* __restrict__ out, int b, int hs0, int SR) {
  __shared__ uint4 lds4[3360];              // 53760 B
  char* smem = (char*)lds4;
  int tid = threadIdx.x;
  int w0 = blockIdx.x * 64;
  int oh0 = blockIdx.y * 2;
  int wave = tid >> 6, lane = tid & 63;
  int wavem = wave >> 1, waven = wave & 1;
  int l15 = lane & 15, l4 = lane >> 4;

  // BN2 constants for this lane's two oc values
  float scl[2], shf[2];
  #pragma unroll
  for (int nf = 0; nf < 2; ++nf) {
    int oc = waven * 32 + nf * 16 + l15;
    float s = g[oc] * rsqrtf(v_[oc] + 1e-5f);
    scl[nf] = s;
    shf[nf] = (cb[oc] - m_[oc]) * s + bt[oc];
  }

  // precomputed LDS fragment addresses
  int aaddr[4][3];
  #pragma unroll
  for (int mf = 0; mf < 4; ++mf)
    #pragma unroll
    for (int kx = 0; kx < 3; ++kx) {
      int col = mf * 16 + l15 + kx;
      aaddr[mf][kx] = wavem * 4224 + (col << 6) + ((l4 << 4) ^ (((col >> 1) & 3) << 4));
    }
  int baddr[2];
  #pragma unroll
  for (int nf = 0; nf < 2; ++nf) {
    int n = waven * 32 + nf * 16 + l15;
    baddr[nf] = LDSB + (n << 6) + ((l4 << 4) ^ (((n >> 1) & 3) << 4));
  }

  f32x4 acc[4][2];
  #pragma unroll
  for (int mf = 0; mf < 4; ++mf)
    #pragma unroll
    for (int nf = 0; nf < 2; ++nf)
      acc[mf][nf] = (f32x4){0.f, 0.f, 0.f, 0.f};

  // B staging decode (constant across chunks)
  int bn = tid >> 2, bslot = tid & 3;
  int bd = LDSB + (bn << 6) + ((bslot << 4) ^ (((bn >> 1) & 3) << 4));

  for (int chunk = 0; chunk < 4; ++chunk) {
    int ic0 = chunk * 32;
    __syncthreads();
    // ---- A stage: 4 rows x 66 cols x 4 slots = 1056 x 16B ----
    uint4 av0, av1, av2, av3, av4;
    int ad0, ad1, ad2, ad3, ad4 = 0;
    av4 = make_uint4(0, 0, 0, 0);
#define ADEC(II, AV, AD) { \
      int i_ = (II); int slot = i_ & 3; int q = i_ >> 2; \
      int r_ = (q * 993) >> 16; int c_ = q - r_ * 66; \
      int wg = w0 - 1 + c_; \
      AD = ((r_ * 66 + c_) << 6) + ((slot << 4) ^ (((c_ >> 1) & 3) << 4)); \
      AV = make_uint4(0, 0, 0, 0); \
      if (wg >= 0 && wg < 512) \
        AV = *(const uint4*)(buf1 + ((((size_t)(oh0 + r_)) << 9) + wg) * 128 + ic0 + slot * 8); \
    }
    ADEC(tid, av0, ad0);
    ADEC(tid + 256, av1, ad1);
    ADEC(tid + 512, av2, ad2);
    ADEC(tid + 768, av3, ad3);
    if (tid < 32) ADEC(tid + 1024, av4, ad4);
#undef ADEC
    // ---- B stage: 9 taps x 32k x 64n ----
    uint4 bv[9];
    const ushort* wsrc = w2t + (size_t)bn * 1152 + ic0 + bslot * 8;
    #pragma unroll
    for (int j = 0; j < 9; ++j) bv[j] = *(const uint4*)(wsrc + j * 128);

    *(uint4*)(smem + ad0) = av0;
    *(uint4*)(smem + ad1) = av1;
    *(uint4*)(smem + ad2) = av2;
    *(uint4*)(smem + ad3) = av3;
    if (tid < 32) *(uint4*)(smem + ad4) = av4;
    #pragma unroll
    for (int j = 0; j < 9; ++j) *(uint4*)(smem + bd + j * 4096) = bv[j];
    __syncthreads();

    // ---- compute: 9 taps x 8 MFMA ----
    #pragma unroll
    for (int ky = 0; ky < 3; ++ky) {
      #pragma unroll
      for (int kx = 0; kx < 3; ++kx) {
        const int tap = ky * 3 + kx;
        bf16x8 bf0 = *(const bf16x8*)(smem + baddr[0] + tap * 4096);
        bf16x8 bf1 = *(const bf16x8*)(smem + baddr[1] + tap * 4096);
        #pragma unroll
        for (int mf = 0; mf < 4; ++mf) {
          bf16x8 af = *(const bf16x8*)(smem + aaddr[mf][kx] + ky * 4224);
          acc[mf][0] = __builtin_amdgcn_mfma_f32_16x16x32_bf16(af, bf0, acc[mf][0], 0, 0, 0);
          acc[mf][1] = __builtin_amdgcn_mfma_f32_16x16x32_bf16(af, bf1, acc[mf][1], 0, 0, 0);
        }
      }
    }
  }

  // ---- epilogue: BN2+ReLU -> LDS scratch [128 px][66] f32 ----
  __syncthreads();
  #pragma unroll
  for (int mf = 0; mf < 4; ++mf)
    #pragma unroll
    for (int nf = 0; nf < 2; ++nf)
      #pragma unroll
      for (int rr = 0; rr < 4; ++rr) {
        int mm = wavem * 64 + mf * 16 + l4 * 4 + rr;
        int oc = waven * 32 + nf * 16 + l15;
        float val = fmaxf(fmaf(acc[mf][nf][rr], scl[nf], shf[nf]), 0.f);
        *(float*)(smem + SCRATCH_OFF + (mm * 66 + oc) * 4) = val;
      }
  // stage w3/b3 (threads 128..255) into the tail of LDS
  if (tid >= 128) {
    int idx = tid - 128;
    #pragma unroll
    for (int j = 0; j < 2; ++j) {
      int ii = idx + j * 128;
      if (ii < 144) *(uint4*)(smem + W3_OFF + ii * 16) = *(const uint4*)(w3 + ii * 4);
    }
    if (idx < NC) *(float*)(smem + B3_OFF + idx * 4) = b3[idx];
  }
  __syncthreads();

  // ---- fused conv3: 128 threads, one pixel each ----
  if (tid < 128) {
    int px = tid;
    const float* w3f = (const float*)(smem + W3_OFF);
    const float* b3f = (const float*)(smem + B3_OFF);
    float a9[NC];
    #pragma unroll
    for (int c = 0; c < NC; ++c) a9[c] = b3f[c];
    #pragma unroll 8
    for (int j = 0; j < 32; ++j) {
      float2 xv = *(const float2*)(smem + SCRATCH_OFF + (px * 66 + 2 * j) * 4);
      #pragma unroll
      for (int c = 0; c < NC; ++c)
        a9[c] = fmaf(xv.x, w3f[c * 64 + 2 * j], fmaf(xv.y, w3f[c * 64 + 2 * j + 1], a9[c]));
    }
    int h = hs0 + oh0 + (px >> 6);
    int w = w0 + (px & 63);
    size_t base = ((size_t)b * NC) * 262144 + (size_t)h * 512 + w;
    #pragma unroll
    for (int c = 0; c < NC; ++c) out[base + (size_t)c * 262144] = a9[c];
  }
}

extern "C" void kernel_launch(void* const* d_in, const int* in_sizes, int n_in,
                              void* d_out, int out_size, void* d_ws, size_t ws_size,
                              hipStream_t stream) {
  const float* hs  = (const float*)d_in[0];
  const int* bbox  = (const int*)d_in[1];
  const int* amask = (const int*)d_in[2];
  const float* pw  = (const float*)d_in[3];
  const float* pb  = (const float*)d_in[4];
  const float* w1  = (const float*)d_in[5];
  const float* c1b = (const float*)d_in[6];
  const float* g1  = (const float*)d_in[7];
  const float* b1  = (const float*)d_in[8];
  const float* m1  = (const float*)d_in[9];
  const float* v1  = (const float*)d_in[10];
  const float* w2  = (const float*)d_in[11];
  const float* c2b = (const float*)d_in[12];
  const float* g2  = (const float*)d_in[13];
  const float* b2  = (const float*)d_in[14];
  const float* m2  = (const float*)d_in[15];
  const float* v2  = (const float*)d_in[16];
  const float* w3  = (const float*)d_in[17];
  const float* b3  = (const float*)d_in[18];
  float* out = (float*)d_out;

  char* wsb = (char*)d_ws;
  float*  feat   = (float*)(wsb + 0);             // 1 MB
  int*    winner = (int*)(wsb + 1048576);         // 2 MB
  float*  G      = (float*)(wsb + 3145728);       // 4.5 MB
  float*  Gall   = (float*)(wsb + 7864320);       // 0.5 MB
  int*    aux    = (int*)(wsb + 8388608);         // 2 MB
  ushort* w2t    = (ushort*)(wsb + 10485760);     // 144 KB (pad to 256 KB)
  ushort* buf1   = (ushort*)(wsb + 10747904);

  int SR = 512;
  while (SR > 32) {
    size_t need = 10747904 + (size_t)(SR + 2) * 131072;
    if (need <= ws_size) break;
    SR >>= 1;
  }

  proj_kernel<<<1024, 256, 0, stream>>>(hs, pw, pb, feat);
  winner_kernel<<<dim3(1024, 2), 256, 0, stream>>>(bbox, amask, winner);
  gtab_kernel<<<256, 128, 0, stream>>>(feat, w1, G, Gall);
  aux_kernel<<<2048, 256, 0, stream>>>(winner, aux);
  w2t_kernel<<<64, 256, 0, stream>>>(w2, w2t);

  int nstripes = 512 / SR;
  for (int b = 0; b < 2; ++b) {
    for (int s = 0; s < nstripes; ++s) {
      int hs0 = s * SR;
      conv1_gather_kernel<<<dim3((SR + 2) * 512 / 32), 256, 0, stream>>>(
          winner, aux, G, Gall, c1b, g1, b1, m1, v1, buf1, b, hs0 - 1);
      conv2_mfma_kernel<<<dim3(8, SR / 2), 256, 0, stream>>>(
          buf1, w2t, c2b, g2, b2, m2, v2, w3, b3, out, b, hs0, SR);
    }
  }
}

// Round 4
// 357.567 us; speedup vs baseline: 19.0147x; 1.1207x over previous
//
#include <hip/hip_runtime.h>
#include <hip/hip_bf16.h>

typedef __bf16 bf16x8 __attribute__((ext_vector_type(8)));
typedef float f32x4 __attribute__((ext_vector_type(4)));

#define HH 512
#define WW 512
#define NC 9
#define LDSB 16896
#define SCRATCH_OFF 0
#define W3_OFF 33792
#define B3_OFF 36096

static __device__ __forceinline__ ushort f2bf(float x) {
  union { float f; unsigned u; } c; c.f = x;
  unsigned r = c.u + 0x7FFFu + ((c.u >> 16) & 1u);
  return (ushort)(r >> 16);
}

// ---------------- K1: features = hs @ proj_w + proj_b (tiled) ----------------
// 128 blocks x 256 thr; wave = 2 rows, lane = 4 cols.
__global__ __launch_bounds__(256) void proj_kernel(
    const float* __restrict__ hs, const float* __restrict__ pw,
    const float* __restrict__ pb, float* __restrict__ feat) {
  int tid = threadIdx.x;
  int wave = __builtin_amdgcn_readfirstlane(tid >> 6);
  int lane = tid & 63;
  int r0 = blockIdx.x * 8 + wave * 2;
  int c0 = lane * 4;
  const float* h0 = hs + (size_t)r0 * 768;
  const float* h1 = h0 + 768;
  float4 bb = *(const float4*)(pb + c0);
  float4 acc0 = bb, acc1 = bb;
  #pragma unroll 4
  for (int k = 0; k < 768; ++k) {
    float4 wv = *(const float4*)(pw + (size_t)k * 256 + c0);
    float a = h0[k], b = h1[k];
    acc0.x = fmaf(a, wv.x, acc0.x); acc0.y = fmaf(a, wv.y, acc0.y);
    acc0.z = fmaf(a, wv.z, acc0.z); acc0.w = fmaf(a, wv.w, acc0.w);
    acc1.x = fmaf(b, wv.x, acc1.x); acc1.y = fmaf(b, wv.y, acc1.y);
    acc1.z = fmaf(b, wv.z, acc1.z); acc1.w = fmaf(b, wv.w, acc1.w);
  }
  *(float4*)(feat + (size_t)r0 * 256 + c0) = acc0;
  *(float4*)(feat + (size_t)(r0 + 1) * 256 + c0) = acc1;
}

// ---------------- K2: winner map via atomic scatter ----------------
// winner[b,h,w] = max valid token s covering the pixel (0 = empty).
__global__ __launch_bounds__(64) void scatter_kernel(
    const int* __restrict__ bbox, const int* __restrict__ amask,
    int* __restrict__ winner) {
  int token = blockIdx.x;          // 0..1023
  int b = token >> 9, s = token & 511;
  if (s == 0) return;
  const int* bb = bbox + (size_t)token * 4;
  int x1 = (bb[0] * 512) / 1000; if (x1 < 0) x1 = 0;
  int y1 = (bb[1] * 512) / 1000; if (y1 < 0) y1 = 0;
  int x2 = (bb[2] * 512) / 1000; if (x2 > 511) x2 = 511;
  int y2 = (bb[3] * 512) / 1000; if (y2 > 511) y2 = 511;
  if (amask[token] != 1 || x2 <= x1 || y2 <= y1) return;
  int lane = threadIdx.x;
  for (int yy = y1; yy < y2; ++yy) {
    int rowbase = (b << 18) + (yy << 9);
    for (int xx = x1 + lane; xx < x2; xx += 64)
      atomicMax(&winner[rowbase + xx], s);
  }
}

// ---------------- K2.5: G tables ----------------
__global__ __launch_bounds__(128) void gtab_kernel(
    const float* __restrict__ feat, const float* __restrict__ w1,
    float* __restrict__ G, float* __restrict__ Gall) {
  int b = blockIdx.x >> 7;
  int s0 = (blockIdx.x & 127) * 4;
  __shared__ float sfeat[4 * 256];
  int oc = threadIdx.x;
  for (int i = oc; i < 1024; i += 128)
    sfeat[i] = feat[(((size_t)b << 9) + s0) * 256 + i];
  __syncthreads();

  float acc[4][9];
  #pragma unroll
  for (int to = 0; to < 4; ++to)
    #pragma unroll
    for (int t = 0; t < 9; ++t) acc[to][t] = 0.f;

  const float* wrow = w1 + (size_t)oc * 2304;
  for (int ic = 0; ic < 256; ++ic) {
    float w[9];
    #pragma unroll
    for (int t = 0; t < 9; ++t) w[t] = wrow[ic * 9 + t];
    #pragma unroll
    for (int to = 0; to < 4; ++to) {
      float f = sfeat[to * 256 + ic];
      #pragma unroll
      for (int t = 0; t < 9; ++t) acc[to][t] = fmaf(f, w[t], acc[to][t]);
    }
  }

  #pragma unroll
  for (int to = 0; to < 4; ++to) {
    int s = s0 + to;
    float msk = (s > 0) ? 1.f : 0.f;
    float sum = 0.f;
    size_t base = (((size_t)b << 9) + s) * 1152;
    #pragma unroll
    for (int t = 0; t < 9; ++t) {
      float vv = acc[to][t] * msk;
      G[base + t * 128 + oc] = vv;
      sum += vv;
    }
    Gall[(((size_t)b << 9) + s) * 128 + oc] = sum;
  }
}

// ---------------- K2.7: w2T[oc][tap*128+ic] bf16 ----------------
__global__ __launch_bounds__(256) void w2t_kernel(
    const float* __restrict__ w2, ushort* __restrict__ w2t) {
  int oc = blockIdx.x;
  for (int k = threadIdx.x; k < 1152; k += 256) {
    int tap = k >> 7, ic = k & 127;
    w2t[(size_t)oc * 1152 + k] = f2bf(w2[(size_t)oc * 1152 + ic * 9 + tap]);
  }
}

// ---------------- K3: conv1 gather + BN1 + ReLU -> buf1 (bf16 NHWC) ----------------
// buf1: [(SR+2) rows][512 w][128 ic] bf16 ; row i <-> global h = hstart + i
// thread per pixel; computes 9-winner window + alleq inline.
__global__ __launch_bounds__(256) void conv1_gather_kernel(
    const int* __restrict__ winner,
    const float* __restrict__ G, const float* __restrict__ Gall,
    const float* __restrict__ cb, const float* __restrict__ g,
    const float* __restrict__ bt, const float* __restrict__ m,
    const float* __restrict__ v,
    ushort* __restrict__ buf1, int b, int hstart) {
  __shared__ float sscl[128], sshf[128];
  int tid = threadIdx.x;
  if (tid < 128) {
    float s = g[tid] * rsqrtf(v[tid] + 1e-5f);
    sscl[tid] = s;
    sshf[tid] = (cb[tid] - m[tid]) * s + bt[tid];
  }
  __syncthreads();
  int px = blockIdx.x * 256 + tid;
  int r = px >> 9, w = px & 511;
  int h = hstart + r;
  ushort* dst = buf1 + (size_t)px * 128;
  if (h < 0 || h >= HH) {
    uint4 z = make_uint4(0, 0, 0, 0);
    #pragma unroll
    for (int j = 0; j < 16; ++j) *(uint4*)(dst + j * 8) = z;
    return;
  }
  const int* wb = winner + (b << 18);
  int win[9];
  #pragma unroll
  for (int ky = 0; ky < 3; ++ky)
    #pragma unroll
    for (int kx = 0; kx < 3; ++kx) {
      int hp = h - 1 + ky, wp = w - 1 + kx;
      int s = 0;
      if (hp >= 0 && hp < HH && wp >= 0 && wp < WW) s = wb[(hp << 9) + wp];
      win[ky * 3 + kx] = s;
    }
  bool alleq = true;
  #pragma unroll
  for (int t = 1; t < 9; ++t) alleq = alleq && (win[t] == win[0]);

  if (alleq) {
    const float4* gp = (const float4*)(Gall + ((((size_t)b << 9) + win[0]) << 7));
    #pragma unroll
    for (int o8 = 0; o8 < 16; ++o8) {
      float4 a0 = gp[o8 * 2], a1 = gp[o8 * 2 + 1];
      const float* sc = &sscl[o8 * 8];
      const float* sh = &sshf[o8 * 8];
      union { ushort us[8]; uint4 v4; } pk;
      pk.us[0] = f2bf(fmaxf(fmaf(a0.x, sc[0], sh[0]), 0.f));
      pk.us[1] = f2bf(fmaxf(fmaf(a0.y, sc[1], sh[1]), 0.f));
      pk.us[2] = f2bf(fmaxf(fmaf(a0.z, sc[2], sh[2]), 0.f));
      pk.us[3] = f2bf(fmaxf(fmaf(a0.w, sc[3], sh[3]), 0.f));
      pk.us[4] = f2bf(fmaxf(fmaf(a1.x, sc[4], sh[4]), 0.f));
      pk.us[5] = f2bf(fmaxf(fmaf(a1.y, sc[5], sh[5]), 0.f));
      pk.us[6] = f2bf(fmaxf(fmaf(a1.z, sc[6], sh[6]), 0.f));
      pk.us[7] = f2bf(fmaxf(fmaf(a1.w, sc[7], sh[7]), 0.f));
      *(uint4*)(dst + o8 * 8) = pk.v4;
    }
  } else {
    size_t off[9];
    #pragma unroll
    for (int t = 0; t < 9; ++t)
      off[t] = ((size_t)((b << 9) + win[t])) * 1152 + t * 128;
    #pragma unroll
    for (int o8 = 0; o8 < 16; ++o8) {
      float4 a0 = make_float4(0, 0, 0, 0), a1 = a0;
      #pragma unroll
      for (int t = 0; t < 9; ++t) {
        const float4* gp = (const float4*)(G + off[t] + o8 * 8);
        float4 g0 = gp[0], g1 = gp[1];
        a0.x += g0.x; a0.y += g0.y; a0.z += g0.z; a0.w += g0.w;
        a1.x += g1.x; a1.y += g1.y; a1.z += g1.z; a1.w += g1.w;
      }
      const float* sc = &sscl[o8 * 8];
      const float* sh = &sshf[o8 * 8];
      union { ushort us[8]; uint4 v4; } pk;
      pk.us[0] = f2bf(fmaxf(fmaf(a0.x, sc[0], sh[0]), 0.f));
      pk.us[1] = f2bf(fmaxf(fmaf(a0.y, sc[1], sh[1]), 0.f));
      pk.us[2] = f2bf(fmaxf(fmaf(a0.z, sc[2], sh[2]), 0.f));
      pk.us[3] = f2bf(fmaxf(fmaf(a0.w, sc[3], sh[3]), 0.f));
      pk.us[4] = f2bf(fmaxf(fmaf(a1.x, sc[4], sh[4]), 0.f));
      pk.us[5] = f2bf(fmaxf(fmaf(a1.y, sc[5], sh[5]), 0.f));
      pk.us[6] = f2bf(fmaxf(fmaf(a1.z, sc[6], sh[6]), 0.f));
      pk.us[7] = f2bf(fmaxf(fmaf(a1.w, sc[7], sh[7]), 0.f));
      *(uint4*)(dst + o8 * 8) = pk.v4;
    }
  }
}

// ---------------- K4: conv2 MFMA (implicit GEMM) + BN2 + ReLU + fused conv3 ----------------
__global__ __launch_bounds__(256) void conv2_mfma_kernel(
    const ushort* __restrict__ buf1, const ushort* __restrict__ w2t,
    const float* __restrict__ cb, const float* __restrict__ g,
    const float* __restrict__ bt, const float* __restrict__ m_,
    const float* __restrict__ v_,
    const float* __restrict__ w3, const float* __restrict__ b3,
    float* __restrict__ out, int b, int hs0, int SR) {
  __shared__ uint4 lds4[3360];              // 53760 B
  char* smem = (char*)lds4;
  int tid = threadIdx.x;
  int w0 = blockIdx.x * 64;
  int oh0 = blockIdx.y * 2;
  int wave = tid >> 6, lane = tid & 63;
  int wavem = wave >> 1, waven = wave & 1;
  int l15 = lane & 15, l4 = lane >> 4;

  float scl[2], shf[2];
  #pragma unroll
  for (int nf = 0; nf < 2; ++nf) {
    int oc = waven * 32 + nf * 16 + l15;
    float s = g[oc] * rsqrtf(v_[oc] + 1e-5f);
    scl[nf] = s;
    shf[nf] = (cb[oc] - m_[oc]) * s + bt[oc];
  }

  int aaddr[4][3];
  #pragma unroll
  for (int mf = 0; mf < 4; ++mf)
    #pragma unroll
    for (int kx = 0; kx < 3; ++kx) {
      int col = mf * 16 + l15 + kx;
      aaddr[mf][kx] = wavem * 4224 + (col << 6) + ((l4 << 4) ^ (((col >> 1) & 3) << 4));
    }
  int baddr[2];
  #pragma unroll
  for (int nf = 0; nf < 2; ++nf) {
    int n = waven * 32 + nf * 16 + l15;
    baddr[nf] = LDSB + (n << 6) + ((l4 << 4) ^ (((n >> 1) & 3) << 4));
  }

  f32x4 acc[4][2];
  #pragma unroll
  for (int mf = 0; mf < 4; ++mf)
    #pragma unroll
    for (int nf = 0; nf < 2; ++nf)
      acc[mf][nf] = (f32x4){0.f, 0.f, 0.f, 0.f};

  int bn = tid >> 2, bslot = tid & 3;
  int bd = LDSB + (bn << 6) + ((bslot << 4) ^ (((bn >> 1) & 3) << 4));

  for (int chunk = 0; chunk < 4; ++chunk) {
    int ic0 = chunk * 32;
    __syncthreads();
    uint4 av0, av1, av2, av3, av4;
    int ad0, ad1, ad2, ad3, ad4 = 0;
    av4 = make_uint4(0, 0, 0, 0);
#define ADEC(II, AV, AD) { \
      int i_ = (II); int slot = i_ & 3; int q = i_ >> 2; \
      int r_ = (q * 993) >> 16; int c_ = q - r_ * 66; \
      int wg = w0 - 1 + c_; \
      AD = ((r_ * 66 + c_) << 6) + ((slot << 4) ^ (((c_ >> 1) & 3) << 4)); \
      AV = make_uint4(0, 0, 0, 0); \
      if (wg >= 0 && wg < 512) \
        AV = *(const uint4*)(buf1 + ((((size_t)(oh0 + r_)) << 9) + wg) * 128 + ic0 + slot * 8); \
    }
    ADEC(tid, av0, ad0);
    ADEC(tid + 256, av1, ad1);
    ADEC(tid + 512, av2, ad2);
    ADEC(tid + 768, av3, ad3);
    if (tid < 32) ADEC(tid + 1024, av4, ad4);
#undef ADEC
    uint4 bv[9];
    const ushort* wsrc = w2t + (size_t)bn * 1152 + ic0 + bslot * 8;
    #pragma unroll
    for (int j = 0; j < 9; ++j) bv[j] = *(const uint4*)(wsrc + j * 128);

    *(uint4*)(smem + ad0) = av0;
    *(uint4*)(smem + ad1) = av1;
    *(uint4*)(smem + ad2) = av2;
    *(uint4*)(smem + ad3) = av3;
    if (tid < 32) *(uint4*)(smem + ad4) = av4;
    #pragma unroll
    for (int j = 0; j < 9; ++j) *(uint4*)(smem + bd + j * 4096) = bv[j];
    __syncthreads();

    #pragma unroll
    for (int ky = 0; ky < 3; ++ky) {
      #pragma unroll
      for (int kx = 0; kx < 3; ++kx) {
        const int tap = ky * 3 + kx;
        bf16x8 bf0 = *(const bf16x8*)(smem + baddr[0] + tap * 4096);
        bf16x8 bf1 = *(const bf16x8*)(smem + baddr[1] + tap * 4096);
        #pragma unroll
        for (int mf = 0; mf < 4; ++mf) {
          bf16x8 af = *(const bf16x8*)(smem + aaddr[mf][kx] + ky * 4224);
          acc[mf][0] = __builtin_amdgcn_mfma_f32_16x16x32_bf16(af, bf0, acc[mf][0], 0, 0, 0);
          acc[mf][1] = __builtin_amdgcn_mfma_f32_16x16x32_bf16(af, bf1, acc[mf][1], 0, 0, 0);
        }
      }
    }
  }

  __syncthreads();
  #pragma unroll
  for (int mf = 0; mf < 4; ++mf)
    #pragma unroll
    for (int nf = 0; nf < 2; ++nf)
      #pragma unroll
      for (int rr = 0; rr < 4; ++rr) {
        int mm = wavem * 64 + mf * 16 + l4 * 4 + rr;
        int oc = waven * 32 + nf * 16 + l15;
        float val = fmaxf(fmaf(acc[mf][nf][rr], scl[nf], shf[nf]), 0.f);
        *(float*)(smem + SCRATCH_OFF + (mm * 66 + oc) * 4) = val;
      }
  if (tid >= 128) {
    int idx = tid - 128;
    #pragma unroll
    for (int j = 0; j < 2; ++j) {
      int ii = idx + j * 128;
      if (ii < 144) *(uint4*)(smem + W3_OFF + ii * 16) = *(const uint4*)(w3 + ii * 4);
    }
    if (idx < NC) *(float*)(smem + B3_OFF + idx * 4) = b3[idx];
  }
  __syncthreads();

  if (tid < 128) {
    int px = tid;
    const float* w3f = (const float*)(smem + W3_OFF);
    const float* b3f = (const float*)(smem + B3_OFF);
    float a9[NC];
    #pragma unroll
    for (int c = 0; c < NC; ++c) a9[c] = b3f[c];
    #pragma unroll 8
    for (int j = 0; j < 32; ++j) {
      float2 xv = *(const float2*)(smem + SCRATCH_OFF + (px * 66 + 2 * j) * 4);
      #pragma unroll
      for (int c = 0; c < NC; ++c)
        a9[c] = fmaf(xv.x, w3f[c * 64 + 2 * j], fmaf(xv.y, w3f[c * 64 + 2 * j + 1], a9[c]));
    }
    int h = hs0 + oh0 + (px >> 6);
    int w = w0 + (px & 63);
    size_t base = ((size_t)b * NC) * 262144 + (size_t)h * 512 + w;
    #pragma unroll
    for (int c = 0; c < NC; ++c) out[base + (size_t)c * 262144] = a9[c];
  }
}

extern "C" void kernel_launch(void* const* d_in, const int* in_sizes, int n_in,
                              void* d_out, int out_size, void* d_ws, size_t ws_size,
                              hipStream_t stream) {
  const float* hs  = (const float*)d_in[0];
  const int* bbox  = (const int*)d_in[1];
  const int* amask = (const int*)d_in[2];
  const float* pw  = (const float*)d_in[3];
  const float* pb  = (const float*)d_in[4];
  const float* w1  = (const float*)d_in[5];
  const float* c1b = (const float*)d_in[6];
  const float* g1  = (const float*)d_in[7];
  const float* b1  = (const float*)d_in[8];
  const float* m1  = (const float*)d_in[9];
  const float* v1  = (const float*)d_in[10];
  const float* w2  = (const float*)d_in[11];
  const float* c2b = (const float*)d_in[12];
  const float* g2  = (const float*)d_in[13];
  const float* b2  = (const float*)d_in[14];
  const float* m2  = (const float*)d_in[15];
  const float* v2  = (const float*)d_in[16];
  const float* w3  = (const float*)d_in[17];
  const float* b3  = (const float*)d_in[18];
  float* out = (float*)d_out;

  char* wsb = (char*)d_ws;
  float*  feat   = (float*)(wsb + 0);             // 1 MB
  int*    winner = (int*)(wsb + 1048576);         // 2 MB
  float*  G      = (float*)(wsb + 3145728);       // 4.5 MB
  float*  Gall   = (float*)(wsb + 7864320);       // 0.5 MB
  ushort* w2t    = (ushort*)(wsb + 10485760);     // 144 KB (pad to 256 KB)
  ushort* buf1   = (ushort*)(wsb + 10747904);

  int SR = 512;
  while (SR > 32) {
    size_t need = 10747904 + (size_t)(SR + 2) * 131072;
    if (need <= ws_size) break;
    SR >>= 1;
  }

  hipMemsetAsync(winner, 0, 2097152, stream);
  proj_kernel<<<128, 256, 0, stream>>>(hs, pw, pb, feat);
  scatter_kernel<<<1024, 64, 0, stream>>>(bbox, amask, winner);
  gtab_kernel<<<256, 128, 0, stream>>>(feat, w1, G, Gall);
  w2t_kernel<<<64, 256, 0, stream>>>(w2, w2t);

  int nstripes = 512 / SR;
  for (int b = 0; b < 2; ++b) {
    for (int s = 0; s < nstripes; ++s) {
      int hs0 = s * SR;
      conv1_gather_kernel<<<dim3((SR + 2) * 512 / 256), 256, 0, stream>>>(
          winner, G, Gall, c1b, g1, b1, m1, v1, buf1, b, hs0 - 1);
      conv2_mfma_kernel<<<dim3(8, SR / 2), 256, 0, stream>>>(
          buf1, w2t, c2b, g2, b2, m2, v2, w3, b3, out, b, hs0, SR);
    }
  }
}

// Round 5
// 285.285 us; speedup vs baseline: 23.8324x; 1.2534x over previous
//
#include <hip/hip_runtime.h>
#include <hip/hip_bf16.h>

typedef __bf16 bf16x8 __attribute__((ext_vector_type(8)));
typedef float f32x4 __attribute__((ext_vector_type(4)));

#define HH 512
#define WW 512
#define NC 9
#define LDSB 16896
#define SCRATCH_OFF 0
#define W3_OFF 33792
#define B3_OFF 36096

static __device__ __forceinline__ ushort f2bf(float x) {
  union { float f; unsigned u; } c; c.f = x;
  unsigned r = c.u + 0x7FFFu + ((c.u >> 16) & 1u);
  return (ushort)(r >> 16);
}

// ---------------- K1: proj GEMM: feat[1024,256] = hs[1024,768] @ pw[768,256] + pb ----------------
// tile M16 x N64 x K128; thread = 1 row x 4 cols.
__global__ __launch_bounds__(256) void proj_gemm_kernel(
    const float* __restrict__ hs, const float* __restrict__ pw,
    const float* __restrict__ pb, float* __restrict__ feat) {
  __shared__ float As[16 * 132];
  __shared__ float4 Bs4[2048];
  int tid = threadIdx.x;
  int r0 = blockIdx.x * 16;
  int n0 = blockIdx.y * 64;
  int r = tid >> 4;
  int c4 = (tid & 15) << 2;
  float4 acc = *(const float4*)(pb + n0 + c4);
  for (int k0 = 0; k0 < 768; k0 += 128) {
    __syncthreads();
    #pragma unroll
    for (int i = 0; i < 8; ++i) {
      int idx = tid + i * 256;
      As[(idx >> 7) * 132 + (idx & 127)] =
          hs[(size_t)(r0 + (idx >> 7)) * 768 + k0 + (idx & 127)];
    }
    #pragma unroll
    for (int i = 0; i < 8; ++i) {
      int idx = tid + i * 256;           // k=idx>>4, n4=(idx&15)<<2
      Bs4[idx] = *(const float4*)(pw + (size_t)(k0 + (idx >> 4)) * 256 + n0 + ((idx & 15) << 2));
    }
    __syncthreads();
    const float* ar = As + r * 132;
    #pragma unroll 8
    for (int k = 0; k < 128; ++k) {
      float a = ar[k];
      float4 bv = Bs4[(k << 4) + (c4 >> 2)];
      acc.x = fmaf(a, bv.x, acc.x); acc.y = fmaf(a, bv.y, acc.y);
      acc.z = fmaf(a, bv.z, acc.z); acc.w = fmaf(a, bv.w, acc.w);
    }
  }
  *(float4*)(feat + (size_t)(r0 + r) * 256 + n0 + c4) = acc;
}

// ---------------- K2: winner map via atomic scatter ----------------
__global__ __launch_bounds__(64) void scatter_kernel(
    const int* __restrict__ bbox, const int* __restrict__ amask,
    int* __restrict__ winner) {
  int token = blockIdx.x;
  int b = token >> 9, s = token & 511;
  if (s == 0) return;
  const int* bb = bbox + (size_t)token * 4;
  int x1 = (bb[0] * 512) / 1000; if (x1 < 0) x1 = 0;
  int y1 = (bb[1] * 512) / 1000; if (y1 < 0) y1 = 0;
  int x2 = (bb[2] * 512) / 1000; if (x2 > 511) x2 = 511;
  int y2 = (bb[3] * 512) / 1000; if (y2 > 511) y2 = 511;
  if (amask[token] != 1 || x2 <= x1 || y2 <= y1) return;
  int lane = threadIdx.x;
  for (int yy = y1; yy < y2; ++yy) {
    int rowbase = (b << 18) + (yy << 9);
    for (int xx = x1 + lane; xx < x2; xx += 64)
      atomicMax(&winner[rowbase + xx], s);
  }
}

// ---------------- K2.4: w1r[ic][tap*128+oc] = w1[oc][ic][tap] (fp32) ----------------
__global__ __launch_bounds__(256) void w1r_kernel(
    const float* __restrict__ w1, float* __restrict__ w1r) {
  int idx = blockIdx.x * 256 + threadIdx.x;   // < 294912
  int ic = idx / 1152, rem = idx - ic * 1152;
  int tap = rem >> 7, oc = rem & 127;
  w1r[idx] = w1[(size_t)oc * 2304 + ic * 9 + tap];
}

// ---------------- K2.5: G GEMM: G[1024,1152] = feat[1024,256] @ w1r[256,1152] ----------------
// zero-mask rows where (row & 511)==0 (token 0 of each batch).
__global__ __launch_bounds__(256) void gtab_gemm_kernel(
    const float* __restrict__ feat, const float* __restrict__ w1r,
    float* __restrict__ G) {
  __shared__ float As[16 * 132];
  __shared__ float4 Bs4[2048];
  int tid = threadIdx.x;
  int r0 = blockIdx.x * 16;
  int n0 = blockIdx.y * 64;
  int r = tid >> 4;
  int c4 = (tid & 15) << 2;
  float4 acc = make_float4(0.f, 0.f, 0.f, 0.f);
  for (int k0 = 0; k0 < 256; k0 += 128) {
    __syncthreads();
    #pragma unroll
    for (int i = 0; i < 8; ++i) {
      int idx = tid + i * 256;
      As[(idx >> 7) * 132 + (idx & 127)] =
          feat[(size_t)(r0 + (idx >> 7)) * 256 + k0 + (idx & 127)];
    }
    #pragma unroll
    for (int i = 0; i < 8; ++i) {
      int idx = tid + i * 256;
      Bs4[idx] = *(const float4*)(w1r + (size_t)(k0 + (idx >> 4)) * 1152 + n0 + ((idx & 15) << 2));
    }
    __syncthreads();
    const float* ar = As + r * 132;
    #pragma unroll 8
    for (int k = 0; k < 128; ++k) {
      float a = ar[k];
      float4 bv = Bs4[(k << 4) + (c4 >> 2)];
      acc.x = fmaf(a, bv.x, acc.x); acc.y = fmaf(a, bv.y, acc.y);
      acc.z = fmaf(a, bv.z, acc.z); acc.w = fmaf(a, bv.w, acc.w);
    }
  }
  int row = r0 + r;
  if ((row & 511) == 0) acc = make_float4(0.f, 0.f, 0.f, 0.f);
  *(float4*)(G + (size_t)row * 1152 + n0 + c4) = acc;
}

// ---------------- K2.6: Gall[row][oc] = sum_t G[row][t*128+oc] ----------------
__global__ __launch_bounds__(256) void gall_kernel(
    const float* __restrict__ G, float* __restrict__ Gall) {
  int idx = blockIdx.x * 256 + threadIdx.x;   // < 131072
  int row = idx >> 7, oc = idx & 127;
  const float* gr = G + (size_t)row * 1152 + oc;
  float s = 0.f;
  #pragma unroll
  for (int t = 0; t < 9; ++t) s += gr[t * 128];
  Gall[idx] = s;
}

// ---------------- K2.7: w2T[oc][tap*128+ic] bf16 ----------------
__global__ __launch_bounds__(256) void w2t_kernel(
    const float* __restrict__ w2, ushort* __restrict__ w2t) {
  int oc = blockIdx.x;
  for (int k = threadIdx.x; k < 1152; k += 256) {
    int tap = k >> 7, ic = k & 127;
    w2t[(size_t)oc * 1152 + k] = f2bf(w2[(size_t)oc * 1152 + ic * 9 + tap]);
  }
}

// ---------------- K3: conv1 gather + BN1 + ReLU -> buf1 (bf16 NHWC) ----------------
__global__ __launch_bounds__(256) void conv1_gather_kernel(
    const int* __restrict__ winner,
    const float* __restrict__ G, const float* __restrict__ Gall,
    const float* __restrict__ cb, const float* __restrict__ g,
    const float* __restrict__ bt, const float* __restrict__ m,
    const float* __restrict__ v,
    ushort* __restrict__ buf1, int b, int hstart) {
  __shared__ float sscl[128], sshf[128];
  int tid = threadIdx.x;
  if (tid < 128) {
    float s = g[tid] * rsqrtf(v[tid] + 1e-5f);
    sscl[tid] = s;
    sshf[tid] = (cb[tid] - m[tid]) * s + bt[tid];
  }
  __syncthreads();
  int px = blockIdx.x * 256 + tid;
  int r = px >> 9, w = px & 511;
  int h = hstart + r;
  ushort* dst = buf1 + (size_t)px * 128;
  if (h < 0 || h >= HH) {
    uint4 z = make_uint4(0, 0, 0, 0);
    #pragma unroll
    for (int j = 0; j < 16; ++j) *(uint4*)(dst + j * 8) = z;
    return;
  }
  const int* wb = winner + (b << 18);
  int win[9];
  #pragma unroll
  for (int ky = 0; ky < 3; ++ky)
    #pragma unroll
    for (int kx = 0; kx < 3; ++kx) {
      int hp = h - 1 + ky, wp = w - 1 + kx;
      int s = 0;
      if (hp >= 0 && hp < HH && wp >= 0 && wp < WW) s = wb[(hp << 9) + wp];
      win[ky * 3 + kx] = s;
    }
  bool alleq = true;
  #pragma unroll
  for (int t = 1; t < 9; ++t) alleq = alleq && (win[t] == win[0]);

  if (alleq) {
    const float4* gp = (const float4*)(Gall + ((((size_t)b << 9) + win[0]) << 7));
    #pragma unroll
    for (int o8 = 0; o8 < 16; ++o8) {
      float4 a0 = gp[o8 * 2], a1 = gp[o8 * 2 + 1];
      const float* sc = &sscl[o8 * 8];
      const float* sh = &sshf[o8 * 8];
      union { ushort us[8]; uint4 v4; } pk;
      pk.us[0] = f2bf(fmaxf(fmaf(a0.x, sc[0], sh[0]), 0.f));
      pk.us[1] = f2bf(fmaxf(fmaf(a0.y, sc[1], sh[1]), 0.f));
      pk.us[2] = f2bf(fmaxf(fmaf(a0.z, sc[2], sh[2]), 0.f));
      pk.us[3] = f2bf(fmaxf(fmaf(a0.w, sc[3], sh[3]), 0.f));
      pk.us[4] = f2bf(fmaxf(fmaf(a1.x, sc[4], sh[4]), 0.f));
      pk.us[5] = f2bf(fmaxf(fmaf(a1.y, sc[5], sh[5]), 0.f));
      pk.us[6] = f2bf(fmaxf(fmaf(a1.z, sc[6], sh[6]), 0.f));
      pk.us[7] = f2bf(fmaxf(fmaf(a1.w, sc[7], sh[7]), 0.f));
      *(uint4*)(dst + o8 * 8) = pk.v4;
    }
  } else {
    size_t off[9];
    #pragma unroll
    for (int t = 0; t < 9; ++t)
      off[t] = ((size_t)((b << 9) + win[t])) * 1152 + t * 128;
    #pragma unroll
    for (int o8 = 0; o8 < 16; ++o8) {
      float4 a0 = make_float4(0, 0, 0, 0), a1 = a0;
      #pragma unroll
      for (int t = 0; t < 9; ++t) {
        const float4* gp = (const float4*)(G + off[t] + o8 * 8);
        float4 g0 = gp[0], g1 = gp[1];
        a0.x += g0.x; a0.y += g0.y; a0.z += g0.z; a0.w += g0.w;
        a1.x += g1.x; a1.y += g1.y; a1.z += g1.z; a1.w += g1.w;
      }
      const float* sc = &sscl[o8 * 8];
      const float* sh = &sshf[o8 * 8];
      union { ushort us[8]; uint4 v4; } pk;
      pk.us[0] = f2bf(fmaxf(fmaf(a0.x, sc[0], sh[0]), 0.f));
      pk.us[1] = f2bf(fmaxf(fmaf(a0.y, sc[1], sh[1]), 0.f));
      pk.us[2] = f2bf(fmaxf(fmaf(a0.z, sc[2], sh[2]), 0.f));
      pk.us[3] = f2bf(fmaxf(fmaf(a0.w, sc[3], sh[3]), 0.f));
      pk.us[4] = f2bf(fmaxf(fmaf(a1.x, sc[4], sh[4]), 0.f));
      pk.us[5] = f2bf(fmaxf(fmaf(a1.y, sc[5], sh[5]), 0.f));
      pk.us[6] = f2bf(fmaxf(fmaf(a1.z, sc[6], sh[6]), 0.f));
      pk.us[7] = f2bf(fmaxf(fmaf(a1.w, sc[7], sh[7]), 0.f));
      *(uint4*)(dst + o8 * 8) = pk.v4;
    }
  }
}

// ---------------- K4: conv2 MFMA (implicit GEMM) + BN2 + ReLU + fused conv3 ----------------
__global__ __launch_bounds__(256) void conv2_mfma_kernel(
    const ushort* __restrict__ buf1, const ushort* __restrict__ w2t,
    const float* __restrict__ cb, const float* __restrict__ g,
    const float* __restrict__ bt, const float* __restrict__ m_,
    const float* __restrict__ v_,
    const float* __restrict__ w3, const float* __restrict__ b3,
    float* __restrict__ out, int b, int hs0, int SR) {
  __shared__ uint4 lds4[3360];              // 53760 B
  char* smem = (char*)lds4;
  int tid = threadIdx.x;
  int w0 = blockIdx.x * 64;
  int oh0 = blockIdx.y * 2;
  int wave = tid >> 6, lane = tid & 63;
  int wavem = wave >> 1, waven = wave & 1;
  int l15 = lane & 15, l4 = lane >> 4;

  float scl[2], shf[2];
  #pragma unroll
  for (int nf = 0; nf < 2; ++nf) {
    int oc = waven * 32 + nf * 16 + l15;
    float s = g[oc] * rsqrtf(v_[oc] + 1e-5f);
    scl[nf] = s;
    shf[nf] = (cb[oc] - m_[oc]) * s + bt[oc];
  }

  int aaddr[4][3];
  #pragma unroll
  for (int mf = 0; mf < 4; ++mf)
    #pragma unroll
    for (int kx = 0; kx < 3; ++kx) {
      int col = mf * 16 + l15 + kx;
      aaddr[mf][kx] = wavem * 4224 + (col << 6) + ((l4 << 4) ^ (((col >> 1) & 3) << 4));
    }
  int baddr[2];
  #pragma unroll
  for (int nf = 0; nf < 2; ++nf) {
    int n = waven * 32 + nf * 16 + l15;
    baddr[nf] = LDSB + (n << 6) + ((l4 << 4) ^ (((n >> 1) & 3) << 4));
  }

  f32x4 acc[4][2];
  #pragma unroll
  for (int mf = 0; mf < 4; ++mf)
    #pragma unroll
    for (int nf = 0; nf < 2; ++nf)
      acc[mf][nf] = (f32x4){0.f, 0.f, 0.f, 0.f};

  int bn = tid >> 2, bslot = tid & 3;
  int bd = LDSB + (bn << 6) + ((bslot << 4) ^ (((bn >> 1) & 3) << 4));

  for (int chunk = 0; chunk < 4; ++chunk) {
    int ic0 = chunk * 32;
    __syncthreads();
    uint4 av0, av1, av2, av3, av4;
    int ad0, ad1, ad2, ad3, ad4 = 0;
    av4 = make_uint4(0, 0, 0, 0);
#define ADEC(II, AV, AD) { \
      int i_ = (II); int slot = i_ & 3; int q = i_ >> 2; \
      int r_ = (q * 993) >> 16; int c_ = q - r_ * 66; \
      int wg = w0 - 1 + c_; \
      AD = ((r_ * 66 + c_) << 6) + ((slot << 4) ^ (((c_ >> 1) & 3) << 4)); \
      AV = make_uint4(0, 0, 0, 0); \
      if (wg >= 0 && wg < 512) \
        AV = *(const uint4*)(buf1 + ((((size_t)(oh0 + r_)) << 9) + wg) * 128 + ic0 + slot * 8); \
    }
    ADEC(tid, av0, ad0);
    ADEC(tid + 256, av1, ad1);
    ADEC(tid + 512, av2, ad2);
    ADEC(tid + 768, av3, ad3);
    if (tid < 32) ADEC(tid + 1024, av4, ad4);
#undef ADEC
    uint4 bv[9];
    const ushort* wsrc = w2t + (size_t)bn * 1152 + ic0 + bslot * 8;
    #pragma unroll
    for (int j = 0; j < 9; ++j) bv[j] = *(const uint4*)(wsrc + j * 128);

    *(uint4*)(smem + ad0) = av0;
    *(uint4*)(smem + ad1) = av1;
    *(uint4*)(smem + ad2) = av2;
    *(uint4*)(smem + ad3) = av3;
    if (tid < 32) *(uint4*)(smem + ad4) = av4;
    #pragma unroll
    for (int j = 0; j < 9; ++j) *(uint4*)(smem + bd + j * 4096) = bv[j];
    __syncthreads();

    #pragma unroll
    for (int ky = 0; ky < 3; ++ky) {
      #pragma unroll
      for (int kx = 0; kx < 3; ++kx) {
        const int tap = ky * 3 + kx;
        bf16x8 bf0 = *(const bf16x8*)(smem + baddr[0] + tap * 4096);
        bf16x8 bf1 = *(const bf16x8*)(smem + baddr[1] + tap * 4096);
        #pragma unroll
        for (int mf = 0; mf < 4; ++mf) {
          bf16x8 af = *(const bf16x8*)(smem + aaddr[mf][kx] + ky * 4224);
          acc[mf][0] = __builtin_amdgcn_mfma_f32_16x16x32_bf16(af, bf0, acc[mf][0], 0, 0, 0);
          acc[mf][1] = __builtin_amdgcn_mfma_f32_16x16x32_bf16(af, bf1, acc[mf][1], 0, 0, 0);
        }
      }
    }
  }

  __syncthreads();
  #pragma unroll
  for (int mf = 0; mf < 4; ++mf)
    #pragma unroll
    for (int nf = 0; nf < 2; ++nf)
      #pragma unroll
      for (int rr = 0; rr < 4; ++rr) {
        int mm = wavem * 64 + mf * 16 + l4 * 4 + rr;
        int oc = waven * 32 + nf * 16 + l15;
        float val = fmaxf(fmaf(acc[mf][nf][rr], scl[nf], shf[nf]), 0.f);
        *(float*)(smem + SCRATCH_OFF + (mm * 66 + oc) * 4) = val;
      }
  if (tid >= 128) {
    int idx = tid - 128;
    #pragma unroll
    for (int j = 0; j < 2; ++j) {
      int ii = idx + j * 128;
      if (ii < 144) *(uint4*)(smem + W3_OFF + ii * 16) = *(const uint4*)(w3 + ii * 4);
    }
    if (idx < NC) *(float*)(smem + B3_OFF + idx * 4) = b3[idx];
  }
  __syncthreads();

  if (tid < 128) {
    int px = tid;
    const float* w3f = (const float*)(smem + W3_OFF);
    const float* b3f = (const float*)(smem + B3_OFF);
    float a9[NC];
    #pragma unroll
    for (int c = 0; c < NC; ++c) a9[c] = b3f[c];
    #pragma unroll 8
    for (int j = 0; j < 32; ++j) {
      float2 xv = *(const float2*)(smem + SCRATCH_OFF + (px * 66 + 2 * j) * 4);
      #pragma unroll
      for (int c = 0; c < NC; ++c)
        a9[c] = fmaf(xv.x, w3f[c * 64 + 2 * j], fmaf(xv.y, w3f[c * 64 + 2 * j + 1], a9[c]));
    }
    int h = hs0 + oh0 + (px >> 6);
    int w = w0 + (px & 63);
    size_t base = ((size_t)b * NC) * 262144 + (size_t)h * 512 + w;
    #pragma unroll
    for (int c = 0; c < NC; ++c) out[base + (size_t)c * 262144] = a9[c];
  }
}

extern "C" void kernel_launch(void* const* d_in, const int* in_sizes, int n_in,
                              void* d_out, int out_size, void* d_ws, size_t ws_size,
                              hipStream_t stream) {
  const float* hs  = (const float*)d_in[0];
  const int* bbox  = (const int*)d_in[1];
  const int* amask = (const int*)d_in[2];
  const float* pw  = (const float*)d_in[3];
  const float* pb  = (const float*)d_in[4];
  const float* w1  = (const float*)d_in[5];
  const float* c1b = (const float*)d_in[6];
  const float* g1  = (const float*)d_in[7];
  const float* b1  = (const float*)d_in[8];
  const float* m1  = (const float*)d_in[9];
  const float* v1  = (const float*)d_in[10];
  const float* w2  = (const float*)d_in[11];
  const float* c2b = (const float*)d_in[12];
  const float* g2  = (const float*)d_in[13];
  const float* b2  = (const float*)d_in[14];
  const float* m2  = (const float*)d_in[15];
  const float* v2  = (const float*)d_in[16];
  const float* w3  = (const float*)d_in[17];
  const float* b3  = (const float*)d_in[18];
  float* out = (float*)d_out;

  char* wsb = (char*)d_ws;
  float*  feat   = (float*)(wsb + 0);             // 1 MB
  int*    winner = (int*)(wsb + 1048576);         // 2 MB
  float*  G      = (float*)(wsb + 3145728);       // 4.5 MB
  float*  Gall   = (float*)(wsb + 7864320);       // 0.5 MB
  float*  w1r    = (float*)(wsb + 8388608);       // 1.18 MB
  ushort* w2t    = (ushort*)(wsb + 10485760);     // 144 KB
  ushort* buf1   = (ushort*)(wsb + 10747904);

  int SR = 512;
  while (SR > 32) {
    size_t need = 10747904 + (size_t)(SR + 2) * 131072;
    if (need <= ws_size) break;
    SR >>= 1;
  }

  hipMemsetAsync(winner, 0, 2097152, stream);
  proj_gemm_kernel<<<dim3(64, 4), 256, 0, stream>>>(hs, pw, pb, feat);
  scatter_kernel<<<1024, 64, 0, stream>>>(bbox, amask, winner);
  w1r_kernel<<<1152, 256, 0, stream>>>(w1, w1r);
  gtab_gemm_kernel<<<dim3(64, 18), 256, 0, stream>>>(feat, w1r, G);
  gall_kernel<<<512, 256, 0, stream>>>(G, Gall);
  w2t_kernel<<<64, 256, 0, stream>>>(w2, w2t);

  int nstripes = 512 / SR;
  for (int b = 0; b < 2; ++b) {
    for (int s = 0; s < nstripes; ++s) {
      int hs0 = s * SR;
      conv1_gather_kernel<<<dim3((SR + 2) * 512 / 256), 256, 0, stream>>>(
          winner, G, Gall, c1b, g1, b1, m1, v1, buf1, b, hs0 - 1);
      conv2_mfma_kernel<<<dim3(8, SR / 2), 256, 0, stream>>>(
          buf1, w2t, c2b, g2, b2, m2, v2, w3, b3, out, b, hs0, SR);
    }
  }
}